// Round 3
// baseline (481.326 us; speedup 1.0000x reference)
//
#include <hip/hip_runtime.h>
#include <hip/hip_bf16.h>

// ---------------------------------------------------------------------------
// Transformer block forward (B=4, T=2048, C=1024, F=4096).
// GEMM engine: 256x256 tile, BK=64, 512 threads (8 waves 2Mx4N), 8-phase
// schedule with counted vmcnt (T3+T4), source-permuted LDS swizzle (T2),
// setprio around MFMA (T5), XCD-aware block swizzle (T1).
// ---------------------------------------------------------------------------

typedef __bf16 bf16x8_t __attribute__((ext_vector_type(8)));
typedef float f32x4_t __attribute__((ext_vector_type(4)));

__device__ __forceinline__ unsigned short f2bf(float f) {
    unsigned int u = __float_as_uint(f);
    u += 0x7fffu + ((u >> 16) & 1u);   // round-to-nearest-even
    return (unsigned short)(u >> 16);
}

__device__ __forceinline__ void gload16(const void* g, void* lds) {
    __builtin_amdgcn_global_load_lds(
        (const __attribute__((address_space(1))) unsigned int*)g,
        (__attribute__((address_space(3))) unsigned int*)lds, 16, 0, 0);
}

enum { EPI_F32 = 0, EPI_BF16 = 1, EPI_BIAS_RELU_BF16 = 2, EPI_RESID_F32 = 3,
       EPI_BIAS_RESID_F32 = 4 };

// C = A @ B^T (+epilogue).  A: [M][lda] bf16 row-major, B: [N][ldb] bf16.
// CSKIP: skip tiles above the causal diagonal. KLIM: Keff = row0+256.
//
// LDS map (bytes): buf*65536 + kk*32768 + op*16384 (op:0=A,1=B), each
// [256 rows][32 k] bf16 stored as 16B chunks c=row*4+s at byte c*16.
// Chunk (row,s) holds global k-slot s^(row&3)  (T2 involution; reads XOR too).
template <int EPI, bool CSKIP, bool KLIM>
__global__ __launch_bounds__(512, 2) void gemm256(
    const unsigned short* __restrict__ A,
    const unsigned short* __restrict__ Bm,
    void* __restrict__ Cout,
    const float* __restrict__ bias,
    const float* __restrict__ resid,
    int M, int N, int K, int lda, int ldb, float scale,
    long long batA, long long batB, long long batC, long long batR)
{
    __shared__ __align__(16) unsigned char lds[131072];

    // T1: bijective XCD swizzle of the flattened block id (nwg % 8 == 0)
    const int gx = gridDim.x;
    const int nwg = gx * gridDim.y;
    int bl = blockIdx.y * gx + blockIdx.x;
    bl = (bl & 7) * (nwg >> 3) + (bl >> 3);
    const int bx = bl % gx, by = bl / gx;

    const int row0 = by * 256, col0 = bx * 256;
    if (CSKIP && col0 > row0) return;

    const int bz = blockIdx.z;
    const unsigned short* Ab = A + (long long)bz * batA + (long long)row0 * lda;
    const unsigned short* Bb = Bm + (long long)bz * batB + (long long)col0 * ldb;

    const int tid = threadIdx.x, lane = tid & 63, wid = tid >> 6;
    const int wrM = (wid >> 2) * 128;     // wave row origin (2 groups)
    const int wcN = (wid & 3) * 64;       // wave col origin (4 groups)
    const int lr = lane & 15, lg = lane >> 4;

    int Keff = K;
    if (KLIM) { int kl = row0 + 256; Keff = kl < K ? kl : K; }
    const int nkt = Keff >> 6;            // K-tiles of 64 (always even here)

    // ---- staging addresses: thread covers chunks c0 = wid*128+lane, c0+64 ----
    int rowc[2], scol[2];
#pragma unroll
    for (int i = 0; i < 2; ++i) {
        const int c = wid * 128 + i * 64 + lane;
        rowc[i] = c >> 2;
        scol[i] = (c & 3) ^ (rowc[i] & 3);          // T2 source permutation
    }
    const unsigned short* gA[2];
    const unsigned short* gB[2];
#pragma unroll
    for (int i = 0; i < 2; ++i) {
        gA[i] = Ab + (long long)rowc[i] * lda + scol[i] * 8;
        gB[i] = Bb + (long long)rowc[i] * ldb + scol[i] * 8;
    }
    const int ldsW = wid * 2048;          // wave's stage window within a region

    // ---- fragment read offsets (bytes, + m/n*1024 + kk*32768 + buf*65536) ----
    const int sw = (lg ^ (lr & 3)) << 4;            // T2 read swizzle
    const int aoff = (wrM + lr) * 64 + sw;          // A region
    const int boff = (wcN + lr) * 64 + sw + 16384;  // B region

    f32x4_t acc[8][4];
#pragma unroll
    for (int m = 0; m < 8; ++m)
#pragma unroll
        for (int n = 0; n < 4; ++n)
            acc[m][n] = (f32x4_t){0.f, 0.f, 0.f, 0.f};

    // stage one (op, kk) half-tile of K-tile kt into buffer buf (2 gload16)
    auto stage = [&](int buf, int kk, int op, int kt) {
        const int ke = kt * 64 + kk * 32;
        const unsigned short* g0 = (op ? gB[0] : gA[0]) + ke;
        const unsigned short* g1 = (op ? gB[1] : gA[1]) + ke;
        unsigned char* d = lds + buf * 65536 + kk * 32768 + op * 16384 + ldsW;
        gload16(g0, d);
        gload16(g1, d + 1024);
    };

    bf16x8_t af[8], bv[2];
    auto dsA = [&](int buf, int kk) {
#pragma unroll
        for (int m = 0; m < 8; ++m)
            af[m] = *(const bf16x8_t*)(lds + buf * 65536 + kk * 32768 + aoff + m * 1024);
    };
    auto dsB = [&](int buf, int kk, int n0) {
#pragma unroll
        for (int j = 0; j < 2; ++j)
            bv[j] = *(const bf16x8_t*)(lds + buf * 65536 + kk * 32768 + boff + (n0 + j) * 1024);
    };
    auto mfma16 = [&](int n0) {
        __builtin_amdgcn_s_setprio(1);
#pragma unroll
        for (int m = 0; m < 8; ++m)
#pragma unroll
            for (int j = 0; j < 2; ++j)
                acc[m][n0 + j] = __builtin_amdgcn_mfma_f32_16x16x32_bf16(
                    af[m], bv[j], acc[m][n0 + j], 0, 0, 0);
        __builtin_amdgcn_s_setprio(0);
    };

    // prologue: fully stage K-tile 0 into buf0 (8 loads, stage order A0,B0,A1,B1)
    stage(0, 0, 0, 0); stage(0, 0, 1, 0); stage(0, 1, 0, 0); stage(0, 1, 1, 0);

    // Steady-state ledger (per-thread loads, oldest->newest), at ph0 of tile t:
    // [A0(t),B0(t),A1(t),B1(t)] (8) + issue A0(t+1) -> 10; vmcnt(6) drains
    // A0(t),B0(t).  At ph2: [A1(t),B1(t),A0',B0'] + A1' -> 10; vmcnt(6) drains
    // A1(t),B1(t).  Last tile: vmcnt(4) / vmcnt(0).
    auto tile = [&](int kt, int buf) {
        const bool pre = (kt + 1 < nkt);
        const int nb = buf ^ 1;
        // ---- ph0: kk0, N{0,1} ----
        if (pre) {
            stage(nb, 0, 0, kt + 1);
            asm volatile("s_waitcnt vmcnt(6)\ns_barrier" ::: "memory");
        } else {
            asm volatile("s_waitcnt vmcnt(4)\ns_barrier" ::: "memory");
        }
        dsA(buf, 0); dsB(buf, 0, 0);
        mfma16(0);
        asm volatile("s_barrier" ::: "memory");
        // ---- ph1: kk0, N{2,3} ----
        if (pre) stage(nb, 0, 1, kt + 1);
        dsB(buf, 0, 2);
        mfma16(2);
        asm volatile("s_barrier" ::: "memory");
        // ---- ph2: kk1, N{0,1} ----
        if (pre) {
            stage(nb, 1, 0, kt + 1);
            asm volatile("s_waitcnt vmcnt(6)\ns_barrier" ::: "memory");
        } else {
            asm volatile("s_waitcnt vmcnt(0)\ns_barrier" ::: "memory");
        }
        dsA(buf, 1); dsB(buf, 1, 0);
        mfma16(0);
        asm volatile("s_barrier" ::: "memory");
        // ---- ph3: kk1, N{2,3} ----
        if (pre) stage(nb, 1, 1, kt + 1);
        dsB(buf, 1, 2);
        mfma16(2);
        asm volatile("s_barrier" ::: "memory");
    };

    for (int kt = 0; kt < nkt; kt += 2) {
        tile(kt, 0);
        tile(kt + 1, 1);
    }

    // ---- epilogue ----
    const int ldc = N;
    float* Cf = (float*)Cout + (long long)bz * batC;
    unsigned short* Cb = (unsigned short*)Cout + (long long)bz * batC;
    const float* R = nullptr;
    if constexpr (EPI == EPI_RESID_F32 || EPI == EPI_BIAS_RESID_F32)
        R = resid + (long long)bz * batR;

#pragma unroll
    for (int m = 0; m < 8; ++m)
#pragma unroll
        for (int n = 0; n < 4; ++n)
#pragma unroll
            for (int j = 0; j < 4; ++j) {
                const int row = row0 + wrM + m * 16 + lg * 4 + j;
                const int col = col0 + wcN + n * 16 + lr;
                const long long idx = (long long)row * ldc + col;
                float v = acc[m][n][j] * scale;
                if constexpr (EPI == EPI_F32) {
                    Cf[idx] = v;
                } else if constexpr (EPI == EPI_BF16) {
                    Cb[idx] = f2bf(v);
                } else if constexpr (EPI == EPI_BIAS_RELU_BF16) {
                    v += bias[col];
                    v = v > 0.f ? v : 0.f;
                    Cb[idx] = f2bf(v);
                } else if constexpr (EPI == EPI_RESID_F32) {
                    Cf[idx] = v + R[idx];
                } else {  // EPI_BIAS_RESID_F32
                    Cf[idx] = v + bias[col] + R[idx];
                }
            }
}

// ------------- transpose + fp32->bf16 convert: in [R][Cc] -> out [Cc][R] ----
__global__ __launch_bounds__(256) void tconv_k(
    const float* __restrict__ in, unsigned short* __restrict__ out,
    int R, int Cc)
{
    __shared__ float t[64][65];
    const int r0 = blockIdx.y * 64, c0 = blockIdx.x * 64;
    const int tid = threadIdx.x;
    const int a = tid >> 4;     // 0..15
    const int b = tid & 15;     // 0..15
#pragma unroll
    for (int i = 0; i < 4; ++i) {
        const int row = a + i * 16;
        float4 v = *(const float4*)(in + (long long)(r0 + row) * Cc + c0 + b * 4);
        t[row][b * 4 + 0] = v.x; t[row][b * 4 + 1] = v.y;
        t[row][b * 4 + 2] = v.z; t[row][b * 4 + 3] = v.w;
    }
    __syncthreads();
#pragma unroll
    for (int i = 0; i < 4; ++i) {
        const int oc = a + i * 16;
        ushort4 o;
        o.x = f2bf(t[b * 4 + 0][oc]);
        o.y = f2bf(t[b * 4 + 1][oc]);
        o.z = f2bf(t[b * 4 + 2][oc]);
        o.w = f2bf(t[b * 4 + 3][oc]);
        *(ushort4*)(out + (long long)(c0 + oc) * R + r0 + b * 4) = o;
    }
}

// ---------------- LayerNorm: one 256-thread block per 1024-elem row --------
__global__ __launch_bounds__(256) void ln_k(
    const float* __restrict__ x, const float* __restrict__ g,
    const float* __restrict__ be, unsigned short* __restrict__ out)
{
    __shared__ float sred[8];
    const long long row = blockIdx.x;
    const int tid = threadIdx.x;
    float4 v = ((const float4*)(x + row * 1024))[tid];
    float s = v.x + v.y + v.z + v.w;
    float q = v.x * v.x + v.y * v.y + v.z * v.z + v.w * v.w;
#pragma unroll
    for (int off = 32; off > 0; off >>= 1) {
        s += __shfl_xor(s, off);
        q += __shfl_xor(q, off);
    }
    if ((tid & 63) == 0) { sred[tid >> 6] = s; sred[4 + (tid >> 6)] = q; }
    __syncthreads();
    s = sred[0] + sred[1] + sred[2] + sred[3];
    q = sred[4] + sred[5] + sred[6] + sred[7];
    const float mean = s * (1.0f / 1024.0f);
    const float var  = q * (1.0f / 1024.0f) - mean * mean;
    const float rstd = rsqrtf(var + 1e-5f);
    float4 gv = ((const float4*)g)[tid];
    float4 bv = ((const float4*)be)[tid];
    ushort4 o;
    o.x = f2bf((v.x - mean) * rstd * gv.x + bv.x);
    o.y = f2bf((v.y - mean) * rstd * gv.y + bv.y);
    o.z = f2bf((v.z - mean) * rstd * gv.z + bv.z);
    o.w = f2bf((v.w - mean) * rstd * gv.w + bv.w);
    *(ushort4*)(out + row * 1024 + tid * 4) = o;
}

// ------------- causal row softmax: S fp32 -> P bf16 (zero-padded) ----------
__global__ __launch_bounds__(256) void softmax_k(
    const float* __restrict__ S, unsigned short* __restrict__ P, int T)
{
    __shared__ float rowl[2048];
    __shared__ float sred[4];
    const int t = blockIdx.x;
    const long long base = ((long long)blockIdx.y * T + t) * (long long)T;
    const float* srow = S + base;
    unsigned short* prow = P + base;
    const int n = t + 1;                       // valid causal length
    const int lim = ((t >> 8) + 1) << 8;       // zero-fill to 256-tile boundary
    const int tid = threadIdx.x;

    const int nv = n >> 2;
    for (int i = tid; i < nv; i += 256)
        ((float4*)rowl)[i] = ((const float4*)srow)[i];
    for (int i = (nv << 2) + tid; i < n; i += 256) rowl[i] = srow[i];
    __syncthreads();

    float mx = -3.0e38f;
    for (int i = tid; i < n; i += 256) mx = fmaxf(mx, rowl[i]);
#pragma unroll
    for (int off = 32; off > 0; off >>= 1) mx = fmaxf(mx, __shfl_xor(mx, off));
    if ((tid & 63) == 0) sred[tid >> 6] = mx;
    __syncthreads();
    mx = fmaxf(fmaxf(sred[0], sred[1]), fmaxf(sred[2], sred[3]));
    __syncthreads();                            // sred reuse

    float sum = 0.f;
    for (int i = tid; i < n; i += 256) {
        float e = __expf(rowl[i] - mx);
        rowl[i] = e;                            // own slots only — no race
        sum += e;
    }
#pragma unroll
    for (int off = 32; off > 0; off >>= 1) sum += __shfl_xor(sum, off);
    if ((tid & 63) == 0) sred[tid >> 6] = sum;
    __syncthreads();
    sum = sred[0] + sred[1] + sred[2] + sred[3];
    const float inv = 1.0f / sum;

    for (int i = tid; i < n; i += 256) prow[i] = f2bf(rowl[i] * inv);
    for (int i = n + tid; i < lim; i += 256) prow[i] = 0;
}

// ---------------------------------------------------------------------------
extern "C" void kernel_launch(void* const* d_in, const int* in_sizes, int n_in,
                              void* d_out, int out_size, void* d_ws, size_t ws_size,
                              hipStream_t stream)
{
    const int B = 4, T = 2048, C = 1024, F = 4096;
    const float* x   = (const float*)d_in[0];
    const float* Wk  = (const float*)d_in[1];
    const float* Wq  = (const float*)d_in[2];
    const float* Wv  = (const float*)d_in[3];
    const float* W1  = (const float*)d_in[4];
    const float* b1  = (const float*)d_in[5];
    const float* W2  = (const float*)d_in[6];
    const float* b2  = (const float*)d_in[7];
    const float* g1  = (const float*)d_in[8];
    const float* be1 = (const float*)d_in[9];
    const float* g2  = (const float*)d_in[10];
    const float* be2 = (const float*)d_in[11];

    char* ws = (char*)d_ws;
    const size_t MB = 1ull << 20;
    unsigned short* h    = (unsigned short*)(ws + 0);         // 16 MiB
    unsigned short* q    = (unsigned short*)(ws + 16 * MB);   // 16 MiB
    unsigned short* k    = (unsigned short*)(ws + 32 * MB);   // 16 MiB
    unsigned short* vT   = (unsigned short*)(ws + 48 * MB);   // 16 MiB  [C][B*T]
    float*          xres = (float*)(ws + 64 * MB);            // 32 MiB
    float*          S    = (float*)(ws + 96 * MB);            // 64 MiB
    unsigned short* ff1  = (unsigned short*)(ws + 96 * MB);   // 64 MiB (aliases S)
    unsigned short* P    = (unsigned short*)(ws + 160 * MB);  // 32 MiB
    unsigned short* wqT  = (unsigned short*)(ws + 192 * MB);  // 2 MiB   [H][C]
    unsigned short* wkT  = (unsigned short*)(ws + 194 * MB);  // 2 MiB
    unsigned short* wvT  = (unsigned short*)(ws + 196 * MB);  // 2 MiB
    unsigned short* w1T  = (unsigned short*)(ws + 198 * MB);  // 8 MiB   [F][C]
    unsigned short* w2T  = (unsigned short*)(ws + 206 * MB);  // 8 MiB   [C][F]

    // transposed weight converts
    tconv_k<<<dim3(16, 16), 256, 0, stream>>>(Wq, wqT, C, C);
    tconv_k<<<dim3(16, 16), 256, 0, stream>>>(Wk, wkT, C, C);
    tconv_k<<<dim3(16, 16), 256, 0, stream>>>(Wv, wvT, C, C);
    tconv_k<<<dim3(64, 16), 256, 0, stream>>>(W1, w1T, C, F);
    tconv_k<<<dim3(16, 64), 256, 0, stream>>>(W2, w2T, F, C);

    // LN1: h = LN(x, g1, be1)
    ln_k<<<dim3(B * T), 256, 0, stream>>>(x, g1, be1, h);

    // q = h @ Wq, k = h @ Wk   (M=8192, N=1024, K=1024)
    dim3 gqk(C / 256, (B * T) / 256, 1);
    gemm256<EPI_BF16, false, false><<<gqk, 512, 0, stream>>>(
        h, wqT, q, nullptr, nullptr, B * T, C, C, C, C, 1.0f, 0, 0, 0, 0);
    gemm256<EPI_BF16, false, false><<<gqk, 512, 0, stream>>>(
        h, wkT, k, nullptr, nullptr, B * T, C, C, C, C, 1.0f, 0, 0, 0, 0);

    // vT = Wv^T @ h^T  (M=C, N=B*T, K=C)
    dim3 gvt((B * T) / 256, C / 256, 1);
    gemm256<EPI_BF16, false, false><<<gvt, 512, 0, stream>>>(
        wvT, h, vT, nullptr, nullptr, C, B * T, C, C, C, 1.0f, 0, 0, 0, 0);

    // S = q @ k^T / 32  (per batch; causal tiles only)
    dim3 gsc(T / 256, T / 256, B);
    gemm256<EPI_F32, true, false><<<gsc, 512, 0, stream>>>(
        q, k, S, nullptr, nullptr, T, T, C, C, C, 0.03125f,
        (long long)T * C, (long long)T * C, (long long)T * T, 0);

    // P = causal softmax(S), bf16, zero-padded to 256-tile boundary
    softmax_k<<<dim3(T, B), 256, 0, stream>>>(S, P, T);

    // xres = x + P @ v  (B = vT [C][B*T], ldb=B*T, batch col-offset T)
    dim3 gsa(C / 256, T / 256, B);
    gemm256<EPI_RESID_F32, false, true><<<gsa, 512, 0, stream>>>(
        P, vT, xres, nullptr, x, T, C, T, T, B * T, 1.0f,
        (long long)T * T, (long long)T, (long long)T * C, (long long)T * C);

    // LN2: h = LN(xres, g2, be2)
    ln_k<<<dim3(B * T), 256, 0, stream>>>(xres, g2, be2, h);

    // ff1 = relu(h @ W1 + b1)   (M=8192, N=4096, K=1024)
    dim3 gf1(F / 256, (B * T) / 256, 1);
    gemm256<EPI_BIAS_RELU_BF16, false, false><<<gf1, 512, 0, stream>>>(
        h, w1T, ff1, b1, nullptr, B * T, F, C, C, C, 1.0f, 0, 0, 0, 0);

    // out = xres + ff1 @ W2 + b2   (M=8192, N=1024, K=4096)
    dim3 gf2(C / 256, (B * T) / 256, 1);
    gemm256<EPI_BIAS_RESID_F32, false, false><<<gf2, 512, 0, stream>>>(
        ff1, w2T, (float*)d_out, b2, xres, B * T, C, F, F, F, 1.0f, 0, 0, 0, 0);
}

// Round 4
// 443.927 us; speedup vs baseline: 1.0842x; 1.0842x over previous
//
#include <hip/hip_runtime.h>
#include <hip/hip_bf16.h>

// ---------------------------------------------------------------------------
// Transformer block forward (B=4, T=2048, C=1024, F=4096).
// GEMM engine: 256x256 tile, BK=64, 512 threads (8 waves 2Mx4N), 8-phase
// schedule: per-phase {ds_read -> stage -> barrier -> lgkm0 -> 16 MFMA ->
// barrier}, counted vmcnt drains (never 0 mid-loop), T2 source-permuted LDS
// swizzle, T5 setprio, T1 XCD block swizzle.
// ---------------------------------------------------------------------------

typedef __bf16 bf16x8_t __attribute__((ext_vector_type(8)));
typedef float f32x4_t __attribute__((ext_vector_type(4)));

__device__ __forceinline__ unsigned short f2bf(float f) {
    unsigned int u = __float_as_uint(f);
    u += 0x7fffu + ((u >> 16) & 1u);   // round-to-nearest-even
    return (unsigned short)(u >> 16);
}

__device__ __forceinline__ void gload16(const void* g, void* lds) {
    __builtin_amdgcn_global_load_lds(
        (const __attribute__((address_space(1))) unsigned int*)g,
        (__attribute__((address_space(3))) unsigned int*)lds, 16, 0, 0);
}

enum { EPI_F32 = 0, EPI_BF16 = 1, EPI_BIAS_RELU_BF16 = 2, EPI_RESID_F32 = 3,
       EPI_BIAS_RESID_F32 = 4 };

// C = A @ B^T (+epilogue).  A: [M][lda] bf16 row-major, B: [N][ldb] bf16.
// CSKIP: skip tiles above the causal diagonal. KLIM: Keff = row0+256.
//
// LDS map (bytes): buf*65536 + kk*32768 + op*16384 (op:0=A,1=B); each region
// [256 rows][32 k] bf16, chunk c=row*4+s at byte c*16; chunk (row,s) holds
// global k-group s^(row&3) (T2 involution; reads XOR the same).
template <int EPI, bool CSKIP, bool KLIM>
__global__ __launch_bounds__(512, 2) void gemm256(
    const unsigned short* __restrict__ A,
    const unsigned short* __restrict__ Bm,
    void* __restrict__ Cout,
    const float* __restrict__ bias,
    const float* __restrict__ resid,
    int M, int N, int K, int lda, int ldb, float scale,
    long long batA, long long batB, long long batC, long long batR)
{
    __shared__ __align__(16) unsigned char lds[131072];

    // T1: bijective XCD swizzle of flattened block id (all grids: nwg%8==0)
    const int gx = gridDim.x;
    const int nwg = gx * gridDim.y;
    int bl = blockIdx.y * gx + blockIdx.x;
    bl = (bl & 7) * (nwg >> 3) + (bl >> 3);
    const int bx = bl % gx, by = bl / gx;

    const int row0 = by * 256, col0 = bx * 256;
    if (CSKIP && col0 > row0) return;

    const int bz = blockIdx.z;
    const unsigned short* Ab = A + (long long)bz * batA + (long long)row0 * lda;
    const unsigned short* Bb = Bm + (long long)bz * batB + (long long)col0 * ldb;

    const int tid = threadIdx.x, lane = tid & 63, wid = tid >> 6;
    const int wrM = (wid >> 2) * 128;     // wave row origin
    const int wcN = (wid & 3) * 64;       // wave col origin
    const int lr = lane & 15, lg = lane >> 4;

    int Keff = K;
    if (KLIM) { int kl = row0 + 256; Keff = kl < K ? kl : K; }
    const int nkt = Keff >> 6;

    // ---- staging: thread covers chunks c = wid*128 + {0,64} + lane ----
    int rowc[2], scol[2];
#pragma unroll
    for (int i = 0; i < 2; ++i) {
        const int c = wid * 128 + i * 64 + lane;
        rowc[i] = c >> 2;
        scol[i] = (c & 3) ^ (rowc[i] & 3);          // T2 source permutation
    }
    const unsigned short* gA[2];
    const unsigned short* gB[2];
#pragma unroll
    for (int i = 0; i < 2; ++i) {
        gA[i] = Ab + (long long)rowc[i] * lda + scol[i] * 8;
        gB[i] = Bb + (long long)rowc[i] * ldb + scol[i] * 8;
    }
    const int ldsW = wid * 2048;

    // ---- fragment read offsets (bytes) ----
    const int sw = (lg ^ (lr & 3)) << 4;            // T2 read swizzle
    const int aoff = (wrM + lr) * 64 + sw;          // + m*1024 within region
    const int boff = (wcN + lr) * 64 + sw + 16384;  // + n*1024

    f32x4_t acc[8][4];
#pragma unroll
    for (int m = 0; m < 8; ++m)
#pragma unroll
        for (int n = 0; n < 4; ++n)
            acc[m][n] = (f32x4_t){0.f, 0.f, 0.f, 0.f};

    auto stage = [&](int buf, int kk, int op, int kt) {
        const int ke = kt * 64 + kk * 32;
        const unsigned short* g0 = (op ? gB[0] : gA[0]) + ke;
        const unsigned short* g1 = (op ? gB[1] : gA[1]) + ke;
        unsigned char* d = lds + buf * 65536 + kk * 32768 + op * 16384 + ldsW;
        gload16(g0, d);
        gload16(g1, d + 1024);
    };

    bf16x8_t af[4], bvv[4];
    auto dsA4 = [&](int buf, int kk, int mq) {
#pragma unroll
        for (int j = 0; j < 4; ++j)
            af[j] = *(const bf16x8_t*)(lds + buf * 65536 + kk * 32768 + aoff
                                       + (mq * 4 + j) * 1024);
    };
    auto dsB4 = [&](int buf, int kk) {
#pragma unroll
        for (int n = 0; n < 4; ++n)
            bvv[n] = *(const bf16x8_t*)(lds + buf * 65536 + kk * 32768 + boff
                                        + n * 1024);
    };
    auto mf16 = [&](int mq) {
        __builtin_amdgcn_s_setprio(1);
#pragma unroll
        for (int j = 0; j < 4; ++j)
#pragma unroll
            for (int n = 0; n < 4; ++n)
                acc[mq * 4 + j][n] = __builtin_amdgcn_mfma_f32_16x16x32_bf16(
                    af[j], bvv[n], acc[mq * 4 + j][n], 0, 0, 0);
        __builtin_amdgcn_s_setprio(0);
    };

    // prologue: stage tile 0 (A0,B0,A1,B1), drain kk0, sync
    stage(0, 0, 0, 0); stage(0, 0, 1, 0); stage(0, 1, 0, 0); stage(0, 1, 1, 0);
    asm volatile("s_waitcnt vmcnt(4)\ns_barrier" ::: "memory");

    // Ledger (per-thread, entering ph0(t)): outstanding = [A1(t),B1(t)] (4).
    // ph0:+A0' (6); ph1:+B0' (8) -> vmcnt(4) drains A1(t),B1(t) (kk1 of t,
    // read at ph2).  ph2:+A1' (6); ph3:+B1' (8) -> vmcnt(4) drains A0',B0'
    // (kk0 of t+1, read at ph0(t+1)).  Drained loads are >=2 phases old.
    for (int kt = 0; kt < nkt; ++kt) {
        const int buf = kt & 1, nb = buf ^ 1;
        const bool pre = kt + 1 < nkt;
        // ---- ph0: kk0, m-quad 0 ----
        dsA4(buf, 0, 0); dsB4(buf, 0);
        if (pre) stage(nb, 0, 0, kt + 1);
        asm volatile("s_barrier\ns_waitcnt lgkmcnt(0)" ::: "memory");
        __builtin_amdgcn_sched_barrier(0);
        mf16(0);
        asm volatile("s_barrier" ::: "memory");
        // ---- ph1: kk0, m-quad 1 (B reused) ----
        dsA4(buf, 0, 1);
        if (pre) {
            stage(nb, 0, 1, kt + 1);
            asm volatile("s_waitcnt vmcnt(4)\ns_barrier\ns_waitcnt lgkmcnt(0)" ::: "memory");
        } else {
            asm volatile("s_waitcnt vmcnt(0)\ns_barrier\ns_waitcnt lgkmcnt(0)" ::: "memory");
        }
        __builtin_amdgcn_sched_barrier(0);
        mf16(1);
        asm volatile("s_barrier" ::: "memory");
        // ---- ph2: kk1, m-quad 0 ----
        dsA4(buf, 1, 0); dsB4(buf, 1);
        if (pre) stage(nb, 1, 0, kt + 1);
        asm volatile("s_barrier\ns_waitcnt lgkmcnt(0)" ::: "memory");
        __builtin_amdgcn_sched_barrier(0);
        mf16(0);
        asm volatile("s_barrier" ::: "memory");
        // ---- ph3: kk1, m-quad 1 ----
        dsA4(buf, 1, 1);
        if (pre) {
            stage(nb, 1, 1, kt + 1);
            asm volatile("s_waitcnt vmcnt(4)\ns_barrier\ns_waitcnt lgkmcnt(0)" ::: "memory");
        } else {
            asm volatile("s_barrier\ns_waitcnt lgkmcnt(0)" ::: "memory");
        }
        __builtin_amdgcn_sched_barrier(0);
        mf16(1);
        asm volatile("s_barrier" ::: "memory");
    }

    // ---- epilogue ----
    const int ldc = N;
    float* Cf = (float*)Cout + (long long)bz * batC;
    unsigned short* Cb = (unsigned short*)Cout + (long long)bz * batC;
    const float* R = nullptr;
    if constexpr (EPI == EPI_RESID_F32 || EPI == EPI_BIAS_RESID_F32)
        R = resid + (long long)bz * batR;

#pragma unroll
    for (int m = 0; m < 8; ++m)
#pragma unroll
        for (int n = 0; n < 4; ++n)
#pragma unroll
            for (int j = 0; j < 4; ++j) {
                const int row = row0 + wrM + m * 16 + lg * 4 + j;
                const int col = col0 + wcN + n * 16 + lr;
                const long long idx = (long long)row * ldc + col;
                float v = acc[m][n][j] * scale;
                if constexpr (EPI == EPI_F32) {
                    Cf[idx] = v;
                } else if constexpr (EPI == EPI_BF16) {
                    Cb[idx] = f2bf(v);
                } else if constexpr (EPI == EPI_BIAS_RELU_BF16) {
                    v += bias[col];
                    v = v > 0.f ? v : 0.f;
                    Cb[idx] = f2bf(v);
                } else if constexpr (EPI == EPI_RESID_F32) {
                    Cf[idx] = v + R[idx];
                } else {  // EPI_BIAS_RESID_F32
                    Cf[idx] = v + bias[col] + R[idx];
                }
            }
}

// ------------- transpose + fp32->bf16 convert: in [R][Cc] -> out [Cc][R] ----
__global__ __launch_bounds__(256) void tconv_k(
    const float* __restrict__ in, unsigned short* __restrict__ out,
    int R, int Cc)
{
    __shared__ float t[64][65];
    const int r0 = blockIdx.y * 64, c0 = blockIdx.x * 64;
    const int tid = threadIdx.x;
    const int a = tid >> 4;
    const int b = tid & 15;
#pragma unroll
    for (int i = 0; i < 4; ++i) {
        const int row = a + i * 16;
        float4 v = *(const float4*)(in + (long long)(r0 + row) * Cc + c0 + b * 4);
        t[row][b * 4 + 0] = v.x; t[row][b * 4 + 1] = v.y;
        t[row][b * 4 + 2] = v.z; t[row][b * 4 + 3] = v.w;
    }
    __syncthreads();
#pragma unroll
    for (int i = 0; i < 4; ++i) {
        const int oc = a + i * 16;
        ushort4 o;
        o.x = f2bf(t[b * 4 + 0][oc]);
        o.y = f2bf(t[b * 4 + 1][oc]);
        o.z = f2bf(t[b * 4 + 2][oc]);
        o.w = f2bf(t[b * 4 + 3][oc]);
        *(ushort4*)(out + (long long)(c0 + oc) * R + r0 + b * 4) = o;
    }
}

// ---------------- LayerNorm: one 256-thread block per 1024-elem row --------
__global__ __launch_bounds__(256) void ln_k(
    const float* __restrict__ x, const float* __restrict__ g,
    const float* __restrict__ be, unsigned short* __restrict__ out)
{
    __shared__ float sred[8];
    const long long row = blockIdx.x;
    const int tid = threadIdx.x;
    float4 v = ((const float4*)(x + row * 1024))[tid];
    float s = v.x + v.y + v.z + v.w;
    float q = v.x * v.x + v.y * v.y + v.z * v.z + v.w * v.w;
#pragma unroll
    for (int off = 32; off > 0; off >>= 1) {
        s += __shfl_xor(s, off);
        q += __shfl_xor(q, off);
    }
    if ((tid & 63) == 0) { sred[tid >> 6] = s; sred[4 + (tid >> 6)] = q; }
    __syncthreads();
    s = sred[0] + sred[1] + sred[2] + sred[3];
    q = sred[4] + sred[5] + sred[6] + sred[7];
    const float mean = s * (1.0f / 1024.0f);
    const float var  = q * (1.0f / 1024.0f) - mean * mean;
    const float rstd = rsqrtf(var + 1e-5f);
    float4 gv = ((const float4*)g)[tid];
    float4 bv = ((const float4*)be)[tid];
    ushort4 o;
    o.x = f2bf((v.x - mean) * rstd * gv.x + bv.x);
    o.y = f2bf((v.y - mean) * rstd * gv.y + bv.y);
    o.z = f2bf((v.z - mean) * rstd * gv.z + bv.z);
    o.w = f2bf((v.w - mean) * rstd * gv.w + bv.w);
    *(ushort4*)(out + row * 1024 + tid * 4) = o;
}

// ------------- causal row softmax: S fp32 -> P bf16 (zero-padded) ----------
__global__ __launch_bounds__(256) void softmax_k(
    const float* __restrict__ S, unsigned short* __restrict__ P, int T)
{
    __shared__ float rowl[2048];
    __shared__ float sred[4];
    const int t = blockIdx.x;
    const long long base = ((long long)blockIdx.y * T + t) * (long long)T;
    const float* srow = S + base;
    unsigned short* prow = P + base;
    const int n = t + 1;                       // valid causal length
    const int lim = ((t >> 8) + 1) << 8;       // zero-fill to 256-tile boundary
    const int tid = threadIdx.x;

    const int nv = n >> 2;
    for (int i = tid; i < nv; i += 256)
        ((float4*)rowl)[i] = ((const float4*)srow)[i];
    for (int i = (nv << 2) + tid; i < n; i += 256) rowl[i] = srow[i];
    __syncthreads();

    float mx = -3.0e38f;
    for (int i = tid; i < n; i += 256) mx = fmaxf(mx, rowl[i]);
#pragma unroll
    for (int off = 32; off > 0; off >>= 1) mx = fmaxf(mx, __shfl_xor(mx, off));
    if ((tid & 63) == 0) sred[tid >> 6] = mx;
    __syncthreads();
    mx = fmaxf(fmaxf(sred[0], sred[1]), fmaxf(sred[2], sred[3]));
    __syncthreads();

    float sum = 0.f;
    for (int i = tid; i < n; i += 256) {
        float e = __expf(rowl[i] - mx);
        rowl[i] = e;
        sum += e;
    }
#pragma unroll
    for (int off = 32; off > 0; off >>= 1) sum += __shfl_xor(sum, off);
    if ((tid & 63) == 0) sred[tid >> 6] = sum;
    __syncthreads();
    sum = sred[0] + sred[1] + sred[2] + sred[3];
    const float inv = 1.0f / sum;

    for (int i = tid; i < n; i += 256) prow[i] = f2bf(rowl[i] * inv);
    for (int i = n + tid; i < lim; i += 256) prow[i] = 0;
}

// ---------------------------------------------------------------------------
extern "C" void kernel_launch(void* const* d_in, const int* in_sizes, int n_in,
                              void* d_out, int out_size, void* d_ws, size_t ws_size,
                              hipStream_t stream)
{
    const int B = 4, T = 2048, C = 1024, F = 4096;
    const float* x   = (const float*)d_in[0];
    const float* Wk  = (const float*)d_in[1];
    const float* Wq  = (const float*)d_in[2];
    const float* Wv  = (const float*)d_in[3];
    const float* W1  = (const float*)d_in[4];
    const float* b1  = (const float*)d_in[5];
    const float* W2  = (const float*)d_in[6];
    const float* b2  = (const float*)d_in[7];
    const float* g1  = (const float*)d_in[8];
    const float* be1 = (const float*)d_in[9];
    const float* g2  = (const float*)d_in[10];
    const float* be2 = (const float*)d_in[11];

    char* ws = (char*)d_ws;
    const size_t MB = 1ull << 20;
    unsigned short* h    = (unsigned short*)(ws + 0);         // 16 MiB
    unsigned short* qk   = (unsigned short*)(ws + 16 * MB);   // 32 MiB  [8192][2048]
    unsigned short* vT   = (unsigned short*)(ws + 48 * MB);   // 16 MiB  [C][8192]
    float*          xres = (float*)(ws + 64 * MB);            // 32 MiB
    float*          S    = (float*)(ws + 96 * MB);            // 64 MiB
    unsigned short* ff1  = (unsigned short*)(ws + 96 * MB);   // 64 MiB (aliases S)
    unsigned short* P    = (unsigned short*)(ws + 160 * MB);  // 32 MiB
    unsigned short* wqkT = (unsigned short*)(ws + 192 * MB);  // 4 MiB   [2C][C]
    unsigned short* wvT  = (unsigned short*)(ws + 196 * MB);  // 2 MiB   [C][C]
    unsigned short* w1T  = (unsigned short*)(ws + 198 * MB);  // 8 MiB   [F][C]
    unsigned short* w2T  = (unsigned short*)(ws + 206 * MB);  // 8 MiB   [C][F]

    // transposed weight converts (q,k fused: wqkT rows 0..C-1 = Wq^T, C..2C-1 = Wk^T)
    tconv_k<<<dim3(16, 16), 256, 0, stream>>>(Wq, wqkT, C, C);
    tconv_k<<<dim3(16, 16), 256, 0, stream>>>(Wk, wqkT + C * C, C, C);
    tconv_k<<<dim3(16, 16), 256, 0, stream>>>(Wv, wvT, C, C);
    tconv_k<<<dim3(64, 16), 256, 0, stream>>>(W1, w1T, C, F);
    tconv_k<<<dim3(16, 64), 256, 0, stream>>>(W2, w2T, F, C);

    // LN1
    ln_k<<<dim3(B * T), 256, 0, stream>>>(x, g1, be1, h);

    // [q|k] = h @ [Wq|Wk]   (M=8192, N=2048, K=1024) -> qk [8192][2048]
    dim3 gqk(2 * C / 256, (B * T) / 256, 1);
    gemm256<EPI_BF16, false, false><<<gqk, 512, 0, stream>>>(
        h, wqkT, qk, nullptr, nullptr, B * T, 2 * C, C, C, C, 1.0f, 0, 0, 0, 0);

    // vT = Wv^T @ h^T  (M=C, N=8192, K=C)
    dim3 gvt((B * T) / 256, C / 256, 1);
    gemm256<EPI_BF16, false, false><<<gvt, 512, 0, stream>>>(
        wvT, h, vT, nullptr, nullptr, C, B * T, C, C, C, 1.0f, 0, 0, 0, 0);

    // S = q @ k^T / 32  (A=qk cols 0..1023, B=qk cols 1024..2047; lda=ldb=2048)
    dim3 gsc(T / 256, T / 256, B);
    gemm256<EPI_F32, true, false><<<gsc, 512, 0, stream>>>(
        qk, qk + C, S, nullptr, nullptr, T, T, C, 2 * C, 2 * C, 0.03125f,
        (long long)T * 2 * C, (long long)T * 2 * C, (long long)T * T, 0);

    // P = causal softmax(S), bf16, zero-padded to 256-tile boundary
    softmax_k<<<dim3(T, B), 256, 0, stream>>>(S, P, T);

    // xres = x + P @ v  (B = vT [C][8192], ldb=8192, batch col-offset T)
    dim3 gsa(C / 256, T / 256, B);
    gemm256<EPI_RESID_F32, false, true><<<gsa, 512, 0, stream>>>(
        P, vT, xres, nullptr, x, T, C, T, T, B * T, 1.0f,
        (long long)T * T, (long long)T, (long long)T * C, (long long)T * C);

    // LN2
    ln_k<<<dim3(B * T), 256, 0, stream>>>(xres, g2, be2, h);

    // ff1 = relu(h @ W1 + b1)   (M=8192, N=4096, K=1024)
    dim3 gf1(F / 256, (B * T) / 256, 1);
    gemm256<EPI_BIAS_RELU_BF16, false, false><<<gf1, 512, 0, stream>>>(
        h, w1T, ff1, b1, nullptr, B * T, F, C, C, C, 1.0f, 0, 0, 0, 0);

    // out = xres + ff1 @ W2 + b2   (M=8192, N=1024, K=4096)
    dim3 gf2(C / 256, (B * T) / 256, 1);
    gemm256<EPI_BIAS_RESID_F32, false, false><<<gf2, 512, 0, stream>>>(
        ff1, w2T, (float*)d_out, b2, xres, B * T, C, F, F, F, 1.0f, 0, 0, 0, 0);
}

// Round 5
// 409.787 us; speedup vs baseline: 1.1746x; 1.0833x over previous
//
#include <hip/hip_runtime.h>
#include <hip/hip_bf16.h>

// ---------------------------------------------------------------------------
// Transformer block forward (B=4, T=2048, C=1024, F=4096).
// GEMM engine: uniform 128x256 tile, BK=64, 512 threads (8 waves 2Mx4N,
// 64x64 per wave), 2 phases per K-tile {8 ds_read -> 3 gload_lds stage ->
// counted vmcnt -> barrier -> lgkm0 -> 16 MFMA -> barrier}, T2 source-
// permuted LDS swizzle, T5 setprio, T1 XCD block swizzle.
// Grid fill >= 256 blocks for every GEMM (fixes round-3/4's half-idle GPU).
// ---------------------------------------------------------------------------

typedef __bf16 bf16x8_t __attribute__((ext_vector_type(8)));
typedef float f32x4_t __attribute__((ext_vector_type(4)));

__device__ __forceinline__ unsigned short f2bf(float f) {
    unsigned int u = __float_as_uint(f);
    u += 0x7fffu + ((u >> 16) & 1u);   // round-to-nearest-even
    return (unsigned short)(u >> 16);
}

__device__ __forceinline__ void gload16(const void* g, void* lds) {
    __builtin_amdgcn_global_load_lds(
        (const __attribute__((address_space(1))) unsigned int*)g,
        (__attribute__((address_space(3))) unsigned int*)lds, 16, 0, 0);
}

enum { EPI_F32 = 0, EPI_BF16 = 1, EPI_BIAS_RELU_BF16 = 2, EPI_RESID_F32 = 3,
       EPI_BIAS_RESID_F32 = 4 };

// C = A @ B^T (+epilogue).  A: [M][lda] bf16 row-major, B: [N][ldb] bf16.
// CSKIP: skip tiles above the causal diagonal. KLIM: Keff = row0+128.
//
// LDS map (bytes): buf*49152 + kk*24576 + {A:0 (8KB), B:8192 (16KB)}.
// Each region [rows][32 k] bf16; 16B chunk c=row*4+s at byte c*16; chunk
// (row,s) holds global k-group s^(row&3) (T2 involution; reads XOR same).
template <int EPI, bool CSKIP, bool KLIM>
__global__ __launch_bounds__(512, 2) void gemm128(
    const unsigned short* __restrict__ A,
    const unsigned short* __restrict__ Bm,
    void* __restrict__ Cout,
    const float* __restrict__ bias,
    const float* __restrict__ resid,
    int M, int N, int K, int lda, int ldb, float scale,
    long long batA, long long batB, long long batC, long long batR)
{
    __shared__ __align__(16) unsigned char lds[98304];

    // T1: bijective XCD swizzle of flattened block id (all grids: nwg%8==0)
    const int gx = gridDim.x;
    const int nwg = gx * gridDim.y;
    int bl = blockIdx.y * gx + blockIdx.x;
    bl = (bl & 7) * (nwg >> 3) + (bl >> 3);
    const int bx = bl % gx, by = bl / gx;

    const int row0 = by * 128, col0 = bx * 256;
    if (CSKIP && col0 > row0) return;   // col0>row0 <=> col0>=row0+128: fully masked

    const int bz = blockIdx.z;
    const unsigned short* Ab = A + (long long)bz * batA + (long long)row0 * lda;
    const unsigned short* Bb = Bm + (long long)bz * batB + (long long)col0 * ldb;

    const int tid = threadIdx.x, lane = tid & 63, wid = tid >> 6;
    const int wrM = (wid >> 2) * 64;      // wave row origin (2 groups x 64)
    const int wcN = (wid & 3) * 64;       // wave col origin (4 groups x 64)
    const int lr = lane & 15, lg = lane >> 4;

    int Keff = K;
    if (KLIM) { int kl = row0 + 128; Keff = kl < K ? kl : K; }
    const int nkt = Keff >> 6;

    // ---- staging: A-half (128x32, 8KB): 1 chunk/thread; B-half (256x32,
    // 16KB): 2 chunks/thread. chunk c -> row c>>2, slot (c&3)^(row&3).
    const int cA = wid * 64 + lane;
    const int rA = cA >> 2;
    const unsigned short* gAp = Ab + (long long)rA * lda + (((cA & 3) ^ (rA & 3)) * 8);
    const unsigned short* gBp[2];
#pragma unroll
    for (int i = 0; i < 2; ++i) {
        const int c = wid * 128 + i * 64 + lane;
        const int r = c >> 2;
        gBp[i] = Bb + (long long)r * ldb + (((c & 3) ^ (r & 3)) * 8);
    }

    // ---- fragment read offsets (bytes within a kk-unit) ----
    const int sw = (lg ^ (lr & 3)) << 4;            // T2 read swizzle
    const int aoff = (wrM + lr) * 64 + sw;          // + m*1024
    const int boff = 8192 + (wcN + lr) * 64 + sw;   // + n*1024

    f32x4_t acc[4][4];
#pragma unroll
    for (int m = 0; m < 4; ++m)
#pragma unroll
        for (int n = 0; n < 4; ++n)
            acc[m][n] = (f32x4_t){0.f, 0.f, 0.f, 0.f};

    auto stageAB = [&](int buf, int kk, int kt2) {   // 3 gloads
        const int ke = kt2 * 64 + kk * 32;
        unsigned char* u = lds + buf * 49152 + kk * 24576;
        gload16(gAp + ke, u + wid * 1024);
        gload16(gBp[0] + ke, u + 8192 + wid * 2048);
        gload16(gBp[1] + ke, u + 8192 + wid * 2048 + 1024);
    };

    bf16x8_t af[4], bvv[4];
    auto dsAB = [&](int buf, int kk) {               // 8 ds_read_b128
        const unsigned char* u = lds + buf * 49152 + kk * 24576;
#pragma unroll
        for (int j = 0; j < 4; ++j)
            af[j] = *(const bf16x8_t*)(u + aoff + j * 1024);
#pragma unroll
        for (int n = 0; n < 4; ++n)
            bvv[n] = *(const bf16x8_t*)(u + boff + n * 1024);
    };
    auto mf16 = [&]() {
        __builtin_amdgcn_s_setprio(1);
#pragma unroll
        for (int j = 0; j < 4; ++j)
#pragma unroll
            for (int n = 0; n < 4; ++n)
                acc[j][n] = __builtin_amdgcn_mfma_f32_16x16x32_bf16(
                    af[j], bvv[n], acc[j][n], 0, 0, 0);
        __builtin_amdgcn_s_setprio(0);
    };

    // prologue: stage tile0 kk0 (3 loads) + kk1 (3); drain kk0
    stageAB(0, 0, 0); stageAB(0, 1, 0);
    asm volatile("s_waitcnt vmcnt(3)\ns_barrier" ::: "memory");

    // Ledger (per-thread, entering ph0(t)): outstanding = kk1(t) (3 loads).
    // ph0: +kk0(t+1) -> 6; vmcnt(3) waits kk1(t) (read at ph1)  -> leaves 3.
    // ph1: +kk1(t+1) -> 6; vmcnt(3) waits kk0(t+1) (read ph0')  -> leaves 3.
    for (int kt = 0; kt < nkt; ++kt) {
        const int buf = kt & 1, nb = buf ^ 1;
        const bool pre = kt + 1 < nkt;
        // ---- ph0: kk0 ----
        dsAB(buf, 0);
        if (pre) {
            stageAB(nb, 0, kt + 1);
            asm volatile("s_waitcnt vmcnt(3)\ns_barrier\ns_waitcnt lgkmcnt(0)" ::: "memory");
        } else {
            asm volatile("s_waitcnt vmcnt(0)\ns_barrier\ns_waitcnt lgkmcnt(0)" ::: "memory");
        }
        __builtin_amdgcn_sched_barrier(0);
        mf16();
        asm volatile("s_barrier" ::: "memory");
        // ---- ph1: kk1 ----
        dsAB(buf, 1);
        if (pre) {
            stageAB(nb, 1, kt + 1);
            asm volatile("s_waitcnt vmcnt(3)\ns_barrier\ns_waitcnt lgkmcnt(0)" ::: "memory");
        } else {
            asm volatile("s_barrier\ns_waitcnt lgkmcnt(0)" ::: "memory");
        }
        __builtin_amdgcn_sched_barrier(0);
        mf16();
        asm volatile("s_barrier" ::: "memory");
    }

    // ---- epilogue ----
    const int ldc = N;
    float* Cf = (float*)Cout + (long long)bz * batC;
    unsigned short* Cb = (unsigned short*)Cout + (long long)bz * batC;
    const float* R = nullptr;
    if constexpr (EPI == EPI_RESID_F32 || EPI == EPI_BIAS_RESID_F32)
        R = resid + (long long)bz * batR;

#pragma unroll
    for (int m = 0; m < 4; ++m)
#pragma unroll
        for (int n = 0; n < 4; ++n)
#pragma unroll
            for (int j = 0; j < 4; ++j) {
                const int row = row0 + wrM + m * 16 + lg * 4 + j;
                const int col = col0 + wcN + n * 16 + lr;
                const long long idx = (long long)row * ldc + col;
                float v = acc[m][n][j] * scale;
                if constexpr (EPI == EPI_F32) {
                    Cf[idx] = v;
                } else if constexpr (EPI == EPI_BF16) {
                    Cb[idx] = f2bf(v);
                } else if constexpr (EPI == EPI_BIAS_RELU_BF16) {
                    v += bias[col];
                    v = v > 0.f ? v : 0.f;
                    Cb[idx] = f2bf(v);
                } else if constexpr (EPI == EPI_RESID_F32) {
                    Cf[idx] = v + R[idx];
                } else {  // EPI_BIAS_RESID_F32
                    Cf[idx] = v + bias[col] + R[idx];
                }
            }
}

// ------------- transpose + fp32->bf16 convert: in [R][Cc] -> out [Cc][R] ----
__global__ __launch_bounds__(256) void tconv_k(
    const float* __restrict__ in, unsigned short* __restrict__ out,
    int R, int Cc)
{
    __shared__ float t[64][65];
    const int r0 = blockIdx.y * 64, c0 = blockIdx.x * 64;
    const int tid = threadIdx.x;
    const int a = tid >> 4;
    const int b = tid & 15;
#pragma unroll
    for (int i = 0; i < 4; ++i) {
        const int row = a + i * 16;
        float4 v = *(const float4*)(in + (long long)(r0 + row) * Cc + c0 + b * 4);
        t[row][b * 4 + 0] = v.x; t[row][b * 4 + 1] = v.y;
        t[row][b * 4 + 2] = v.z; t[row][b * 4 + 3] = v.w;
    }
    __syncthreads();
#pragma unroll
    for (int i = 0; i < 4; ++i) {
        const int oc = a + i * 16;
        ushort4 o;
        o.x = f2bf(t[b * 4 + 0][oc]);
        o.y = f2bf(t[b * 4 + 1][oc]);
        o.z = f2bf(t[b * 4 + 2][oc]);
        o.w = f2bf(t[b * 4 + 3][oc]);
        *(ushort4*)(out + (long long)(c0 + oc) * R + r0 + b * 4) = o;
    }
}

// ---------------- LayerNorm: one 256-thread block per 1024-elem row --------
__global__ __launch_bounds__(256) void ln_k(
    const float* __restrict__ x, const float* __restrict__ g,
    const float* __restrict__ be, unsigned short* __restrict__ out)
{
    __shared__ float sred[8];
    const long long row = blockIdx.x;
    const int tid = threadIdx.x;
    float4 v = ((const float4*)(x + row * 1024))[tid];
    float s = v.x + v.y + v.z + v.w;
    float q = v.x * v.x + v.y * v.y + v.z * v.z + v.w * v.w;
#pragma unroll
    for (int off = 32; off > 0; off >>= 1) {
        s += __shfl_xor(s, off);
        q += __shfl_xor(q, off);
    }
    if ((tid & 63) == 0) { sred[tid >> 6] = s; sred[4 + (tid >> 6)] = q; }
    __syncthreads();
    s = sred[0] + sred[1] + sred[2] + sred[3];
    q = sred[4] + sred[5] + sred[6] + sred[7];
    const float mean = s * (1.0f / 1024.0f);
    const float var  = q * (1.0f / 1024.0f) - mean * mean;
    const float rstd = rsqrtf(var + 1e-5f);
    float4 gv = ((const float4*)g)[tid];
    float4 bv = ((const float4*)be)[tid];
    ushort4 o;
    o.x = f2bf((v.x - mean) * rstd * gv.x + bv.x);
    o.y = f2bf((v.y - mean) * rstd * gv.y + bv.y);
    o.z = f2bf((v.z - mean) * rstd * gv.z + bv.z);
    o.w = f2bf((v.w - mean) * rstd * gv.w + bv.w);
    *(ushort4*)(out + row * 1024 + tid * 4) = o;
}

// ------------- causal row softmax: S fp32 -> P bf16 (zero-padded) ----------
__global__ __launch_bounds__(256) void softmax_k(
    const float* __restrict__ S, unsigned short* __restrict__ P, int T)
{
    __shared__ float rowl[2048];
    __shared__ float sred[4];
    const int t = blockIdx.x;
    const long long base = ((long long)blockIdx.y * T + t) * (long long)T;
    const float* srow = S + base;
    unsigned short* prow = P + base;
    const int n = t + 1;                       // valid causal length
    const int lim = ((t >> 8) + 1) << 8;       // zero-fill to 256 boundary
    const int tid = threadIdx.x;

    const int nv = n >> 2;
    for (int i = tid; i < nv; i += 256)
        ((float4*)rowl)[i] = ((const float4*)srow)[i];
    for (int i = (nv << 2) + tid; i < n; i += 256) rowl[i] = srow[i];
    __syncthreads();

    float mx = -3.0e38f;
    for (int i = tid; i < n; i += 256) mx = fmaxf(mx, rowl[i]);
#pragma unroll
    for (int off = 32; off > 0; off >>= 1) mx = fmaxf(mx, __shfl_xor(mx, off));
    if ((tid & 63) == 0) sred[tid >> 6] = mx;
    __syncthreads();
    mx = fmaxf(fmaxf(sred[0], sred[1]), fmaxf(sred[2], sred[3]));
    __syncthreads();

    float sum = 0.f;
    for (int i = tid; i < n; i += 256) {
        float e = __expf(rowl[i] - mx);
        rowl[i] = e;
        sum += e;
    }
#pragma unroll
    for (int off = 32; off > 0; off >>= 1) sum += __shfl_xor(sum, off);
    if ((tid & 63) == 0) sred[tid >> 6] = sum;
    __syncthreads();
    sum = sred[0] + sred[1] + sred[2] + sred[3];
    const float inv = 1.0f / sum;

    for (int i = tid; i < n; i += 256) prow[i] = f2bf(rowl[i] * inv);
    for (int i = n + tid; i < lim; i += 256) prow[i] = 0;
}

// ---------------------------------------------------------------------------
extern "C" void kernel_launch(void* const* d_in, const int* in_sizes, int n_in,
                              void* d_out, int out_size, void* d_ws, size_t ws_size,
                              hipStream_t stream)
{
    const int B = 4, T = 2048, C = 1024, F = 4096;
    const float* x   = (const float*)d_in[0];
    const float* Wk  = (const float*)d_in[1];
    const float* Wq  = (const float*)d_in[2];
    const float* Wv  = (const float*)d_in[3];
    const float* W1  = (const float*)d_in[4];
    const float* b1  = (const float*)d_in[5];
    const float* W2  = (const float*)d_in[6];
    const float* b2  = (const float*)d_in[7];
    const float* g1  = (const float*)d_in[8];
    const float* be1 = (const float*)d_in[9];
    const float* g2  = (const float*)d_in[10];
    const float* be2 = (const float*)d_in[11];

    char* ws = (char*)d_ws;
    const size_t MB = 1ull << 20;
    unsigned short* h    = (unsigned short*)(ws + 0);         // 16 MiB
    unsigned short* qk   = (unsigned short*)(ws + 16 * MB);   // 32 MiB  [8192][2048]
    unsigned short* vT   = (unsigned short*)(ws + 48 * MB);   // 16 MiB  [C][8192]
    float*          xres = (float*)(ws + 64 * MB);            // 32 MiB
    float*          S    = (float*)(ws + 96 * MB);            // 64 MiB
    unsigned short* ff1  = (unsigned short*)(ws + 96 * MB);   // 64 MiB (aliases S)
    unsigned short* P    = (unsigned short*)(ws + 160 * MB);  // 32 MiB
    unsigned short* wqkT = (unsigned short*)(ws + 192 * MB);  // 4 MiB   [2C][C]
    unsigned short* wvT  = (unsigned short*)(ws + 196 * MB);  // 2 MiB   [C][C]
    unsigned short* w1T  = (unsigned short*)(ws + 198 * MB);  // 8 MiB   [F][C]
    unsigned short* w2T  = (unsigned short*)(ws + 206 * MB);  // 8 MiB   [C][F]

    // transposed weight converts (q,k fused)
    tconv_k<<<dim3(16, 16), 256, 0, stream>>>(Wq, wqkT, C, C);
    tconv_k<<<dim3(16, 16), 256, 0, stream>>>(Wk, wqkT + C * C, C, C);
    tconv_k<<<dim3(16, 16), 256, 0, stream>>>(Wv, wvT, C, C);
    tconv_k<<<dim3(64, 16), 256, 0, stream>>>(W1, w1T, C, F);
    tconv_k<<<dim3(16, 64), 256, 0, stream>>>(W2, w2T, F, C);

    // LN1
    ln_k<<<dim3(B * T), 256, 0, stream>>>(x, g1, be1, h);

    // [q|k] = h @ [Wq|Wk]   (M=8192, N=2048, K=1024) -> 512 blocks
    dim3 gqk(2 * C / 256, (B * T) / 128, 1);
    gemm128<EPI_BF16, false, false><<<gqk, 512, 0, stream>>>(
        h, wqkT, qk, nullptr, nullptr, B * T, 2 * C, C, C, C, 1.0f, 0, 0, 0, 0);

    // vT = Wv^T @ h^T  (M=C, N=8192, K=C) -> 256 blocks
    dim3 gvt((B * T) / 256, C / 128, 1);
    gemm128<EPI_BF16, false, false><<<gvt, 512, 0, stream>>>(
        wvT, h, vT, nullptr, nullptr, C, B * T, C, C, C, 1.0f, 0, 0, 0, 0);

    // S = q @ k^T / 32  (per batch; causal tiles only) -> 288 alive
    dim3 gsc(T / 256, T / 128, B);
    gemm128<EPI_F32, true, false><<<gsc, 512, 0, stream>>>(
        qk, qk + C, S, nullptr, nullptr, T, T, C, 2 * C, 2 * C, 0.03125f,
        (long long)T * 2 * C, (long long)T * 2 * C, (long long)T * T, 0);

    // P = causal softmax(S), bf16, zero-padded
    softmax_k<<<dim3(T, B), 256, 0, stream>>>(S, P, T);

    // xres = x + P @ v  (B = vT [C][8192]) -> 256 blocks
    dim3 gsa(C / 256, T / 128, B);
    gemm128<EPI_RESID_F32, false, true><<<gsa, 512, 0, stream>>>(
        P, vT, xres, nullptr, x, T, C, T, T, B * T, 1.0f,
        (long long)T * T, (long long)T, (long long)T * C, (long long)T * C);

    // LN2
    ln_k<<<dim3(B * T), 256, 0, stream>>>(xres, g2, be2, h);

    // ff1 = relu(h @ W1 + b1)   (M=8192, N=4096, K=1024) -> 1024 blocks
    dim3 gf1(F / 256, (B * T) / 128, 1);
    gemm128<EPI_BIAS_RELU_BF16, false, false><<<gf1, 512, 0, stream>>>(
        h, w1T, ff1, b1, nullptr, B * T, F, C, C, C, 1.0f, 0, 0, 0, 0);

    // out = xres + ff1 @ W2 + b2   (M=8192, N=1024, K=4096) -> 256 blocks
    dim3 gf2(C / 256, (B * T) / 128, 1);
    gemm128<EPI_BIAS_RESID_F32, false, false><<<gf2, 512, 0, stream>>>(
        ff1, w2T, (float*)d_out, b2, xres, B * T, C, F, F, F, 1.0f, 0, 0, 0, 0);
}

// Round 6
// 404.461 us; speedup vs baseline: 1.1900x; 1.0132x over previous
//
#include <hip/hip_runtime.h>
#include <hip/hip_bf16.h>

// ---------------------------------------------------------------------------
// Transformer block forward (B=4, T=2048, C=1024, F=4096).
// GEMM engine: 256x256 tile, BK=64, 512 threads (8 waves 2Mx4N, 128x64 per
// wave, acc[8][4]).  4 phases per K-tile, each: {ds_read subtile -> stage one
// 16KB region of next tile -> vmcnt(4) -> barrier -> lgkm0 -> 16 MFMA ->
// barrier}.  Counted-vmcnt ledger: drained loads are always >=2 phases old;
// never vmcnt(0) mid-loop.  T2 swizzle uses (row>>2)&3 (8 bank-quads -> free
// 2-way).  T5 setprio, T1 bijective XCD swizzle.
// Grid fill: qkv fused (384 blk), ff1 512, ff2 split-K z=2 (256), pv 128,
// scores 144 alive.
// ---------------------------------------------------------------------------

typedef __bf16 bf16x8_t __attribute__((ext_vector_type(8)));
typedef float f32x4_t __attribute__((ext_vector_type(4)));

__device__ __forceinline__ unsigned short f2bf(float f) {
    unsigned int u = __float_as_uint(f);
    u += 0x7fffu + ((u >> 16) & 1u);   // round-to-nearest-even
    return (unsigned short)(u >> 16);
}
__device__ __forceinline__ float bf2f(unsigned short u) {
    return __uint_as_float((unsigned int)u << 16);
}

__device__ __forceinline__ void gload16(const void* g, void* lds) {
    __builtin_amdgcn_global_load_lds(
        (const __attribute__((address_space(1))) unsigned int*)g,
        (__attribute__((address_space(3))) unsigned int*)lds, 16, 0, 0);
}

__device__ __forceinline__ void wait_bar(int w) {
    // w = vmcnt target before the barrier; -1 = no vmcnt wait
    if (w == 4)
        asm volatile("s_waitcnt vmcnt(4)\ns_barrier\ns_waitcnt lgkmcnt(0)" ::: "memory");
    else if (w == 2)
        asm volatile("s_waitcnt vmcnt(2)\ns_barrier\ns_waitcnt lgkmcnt(0)" ::: "memory");
    else if (w == 0)
        asm volatile("s_waitcnt vmcnt(0)\ns_barrier\ns_waitcnt lgkmcnt(0)" ::: "memory");
    else
        asm volatile("s_barrier\ns_waitcnt lgkmcnt(0)" ::: "memory");
}

enum { EPI_F32 = 0, EPI_BF16 = 1, EPI_BIAS_RELU_BF16 = 2, EPI_RESID_F32 = 3,
       EPI_BIAS_RESID_F32 = 4 };

// C = A @ B^T (+epilogue).  A: [M][lda] bf16 row-major, B: [N][ldb] bf16.
// CSKIP: skip tiles above causal diagonal.  KLIM: Keff = row0+256.
// LDS (bytes): buf*65536 + kk*32768 + op*16384 (op:0=A,1=B); region = 256
// rows x 32 k bf16; 16B chunk c=row*4+s at byte c*16; LDS(row,s) holds global
// k-slot s ^ ((row>>2)&3); reads XOR the same.
template <int EPI, bool CSKIP, bool KLIM>
__global__ __launch_bounds__(512, 2) void gemm256(
    const unsigned short* __restrict__ A,
    const unsigned short* __restrict__ Bm,
    void* __restrict__ Cout,
    const float* __restrict__ bias,
    const float* __restrict__ resid,
    int M, int N, int K, int lda, int ldb, float scale,
    long long batA, long long batB, long long batC, long long batR)
{
    __shared__ __align__(16) unsigned char lds[131072];

    // T1: bijective XCD swizzle of flattened block id (all grids: nwg%8==0)
    const int gx = gridDim.x;
    const int nwg = gx * gridDim.y;
    int bl = blockIdx.y * gx + blockIdx.x;
    bl = (bl & 7) * (nwg >> 3) + (bl >> 3);
    const int bx = bl % gx, by = bl / gx;

    const int row0 = by * 256, col0 = bx * 256;
    if (CSKIP && col0 > row0) return;

    const int bz = blockIdx.z;
    const unsigned short* Ab = A + (long long)bz * batA + (long long)row0 * lda;
    const unsigned short* Bb = Bm + (long long)bz * batB + (long long)col0 * ldb;

    const int tid = threadIdx.x, lane = tid & 63, wid = tid >> 6;
    const int wrM = (wid >> 2) * 128;     // wave row origin (2 x 128)
    const int wcN = (wid & 3) * 64;       // wave col origin (4 x 64)
    const int lr = lane & 15, lg = lane >> 4;

    int Keff = K;
    if (KLIM) { int kl = row0 + 256; Keff = kl < K ? kl : K; }
    const int nkt = Keff >> 6;            // K-tiles of 64 (all calls: nkt>=4)

    // ---- staging: wave covers chunks [wid*128, wid*128+128), 2 per thread
    const int c0 = wid * 128 + lane;
    const int crow = c0 >> 2;                          // +16 for second chunk
    const int sg = (c0 & 3) ^ ((c0 >> 4) & 3);          // T2 source slot
    const unsigned short* gA0 = Ab + (long long)crow * lda + sg * 8;
    const unsigned short* gA1 = gA0 + 16ll * lda;
    const unsigned short* gB0 = Bb + (long long)crow * ldb + sg * 8;
    const unsigned short* gB1 = gB0 + 16ll * ldb;

    // ---- fragment read offsets (bytes within region) ----
    const int sw = (lg ^ ((lr >> 2) & 3)) << 4;        // T2 read swizzle
    const int aoff = (wrM + lr) * 64 + sw;             // + m*1024
    const int boff = 16384 + (wcN + lr) * 64 + sw;     // + n*1024

    f32x4_t acc[8][4];
#pragma unroll
    for (int m = 0; m < 8; ++m)
#pragma unroll
        for (int n = 0; n < 4; ++n)
            acc[m][n] = (f32x4_t){0.f, 0.f, 0.f, 0.f};

    // stage region r (0=A-kk0,1=B-kk0,2=A-kk1,3=B-kk1) of tile ktn into buf b
    auto stageR = [&](int b, int r, int ktn) {
        const int kk = r >> 1, op = r & 1;
        const int ke = ktn * 64 + kk * 32;
        unsigned char* d = lds + b * 65536 + kk * 32768 + op * 16384 + wid * 2048;
        const unsigned short* g0 = (op ? gB0 : gA0) + ke;
        const unsigned short* g1 = (op ? gB1 : gA1) + ke;
        gload16(g0, d);
        gload16(g1, d + 1024);
    };

    bf16x8_t af[4], bv[4];
    auto dsA4 = [&](int b, int kk, int mq) {
        const unsigned char* u = lds + b * 65536 + kk * 32768;
#pragma unroll
        for (int j = 0; j < 4; ++j)
            af[j] = *(const bf16x8_t*)(u + aoff + (mq * 4 + j) * 1024);
    };
    auto dsB4 = [&](int b, int kk) {
        const unsigned char* u = lds + b * 65536 + kk * 32768;
#pragma unroll
        for (int n = 0; n < 4; ++n)
            bv[n] = *(const bf16x8_t*)(u + boff + n * 1024);
    };
    auto mf16 = [&](int mq) {
        __builtin_amdgcn_s_setprio(1);
#pragma unroll
        for (int j = 0; j < 4; ++j)
#pragma unroll
            for (int n = 0; n < 4; ++n)
                acc[mq * 4 + j][n] = __builtin_amdgcn_mfma_f32_16x16x32_bf16(
                    af[j], bv[n], acc[mq * 4 + j][n], 0, 0, 0);
        __builtin_amdgcn_s_setprio(0);
    };

    // prologue: stage tile0 fully (A0,B0,A1,B1 = 8 gloads); drain A0,B0.
    stageR(0, 0, 0); stageR(0, 1, 0); stageR(0, 2, 0); stageR(0, 3, 0);
    asm volatile("s_waitcnt vmcnt(4)\ns_barrier" ::: "memory");

    // Steady ledger (per-thread, entering ph0 of tile t): outstanding =
    // [A1(t),B1(t)] (4).  ph0:+A0' ->6, vmcnt(4) drains A1(t) (read ph2).
    // ph1:+B0' ->6, drains B1(t) (read ph2).  ph2:+A1' ->6, drains A0'.
    // ph3:+B1' ->6, drains B0'.  Every drained load is >=2 phases old.
    int kt = 0;
    for (; kt < nkt - 1; ++kt) {
        const int buf = kt & 1, nb = buf ^ 1;
        // ph0: kk0, m-quad 0
        dsA4(buf, 0, 0); dsB4(buf, 0);
        stageR(nb, 0, kt + 1);
        wait_bar(4); __builtin_amdgcn_sched_barrier(0);
        mf16(0);
        asm volatile("s_barrier" ::: "memory");
        // ph1: kk0, m-quad 1 (B reused from regs)
        dsA4(buf, 0, 1);
        stageR(nb, 1, kt + 1);
        wait_bar(4); __builtin_amdgcn_sched_barrier(0);
        mf16(1);
        asm volatile("s_barrier" ::: "memory");
        // ph2: kk1, m-quad 0
        dsA4(buf, 1, 0); dsB4(buf, 1);
        stageR(nb, 2, kt + 1);
        wait_bar(4); __builtin_amdgcn_sched_barrier(0);
        mf16(0);
        asm volatile("s_barrier" ::: "memory");
        // ph3: kk1, m-quad 1
        dsA4(buf, 1, 1);
        stageR(nb, 3, kt + 1);
        wait_bar(4); __builtin_amdgcn_sched_barrier(0);
        mf16(1);
        asm volatile("s_barrier" ::: "memory");
    }
    {   // tail tile: no staging; drain A1,B1(last) before ph2's reads
        const int buf = kt & 1;
        dsA4(buf, 0, 0); dsB4(buf, 0);
        wait_bar(2); __builtin_amdgcn_sched_barrier(0);
        mf16(0);
        asm volatile("s_barrier" ::: "memory");
        dsA4(buf, 0, 1);
        wait_bar(0); __builtin_amdgcn_sched_barrier(0);
        mf16(1);
        asm volatile("s_barrier" ::: "memory");
        dsA4(buf, 1, 0); dsB4(buf, 1);
        wait_bar(-1); __builtin_amdgcn_sched_barrier(0);
        mf16(0);
        asm volatile("s_barrier" ::: "memory");
        dsA4(buf, 1, 1);
        wait_bar(-1); __builtin_amdgcn_sched_barrier(0);
        mf16(1);
        asm volatile("s_barrier" ::: "memory");
    }

    // ---- epilogue ----
    const int ldc = N;
    float* Cf = (float*)Cout + (long long)bz * batC;
    unsigned short* Cb = (unsigned short*)Cout + (long long)bz * batC;
    const float* R = nullptr;
    if constexpr (EPI == EPI_RESID_F32 || EPI == EPI_BIAS_RESID_F32)
        R = resid + (long long)bz * batR;

#pragma unroll
    for (int m = 0; m < 8; ++m)
#pragma unroll
        for (int n = 0; n < 4; ++n)
#pragma unroll
            for (int j = 0; j < 4; ++j) {
                const int row = row0 + wrM + m * 16 + lg * 4 + j;
                const int col = col0 + wcN + n * 16 + lr;
                const long long idx = (long long)row * ldc + col;
                float v = acc[m][n][j] * scale;
                if constexpr (EPI == EPI_F32) {
                    Cf[idx] = v;
                } else if constexpr (EPI == EPI_BF16) {
                    Cb[idx] = f2bf(v);
                } else if constexpr (EPI == EPI_BIAS_RELU_BF16) {
                    v += bias[col];
                    v = v > 0.f ? v : 0.f;
                    Cb[idx] = f2bf(v);
                } else if constexpr (EPI == EPI_RESID_F32) {
                    Cf[idx] = v + R[idx];
                } else {  // EPI_BIAS_RESID_F32
                    Cf[idx] = v + bias[col] + R[idx];
                }
            }
}

// ------------- transpose + fp32->bf16 convert: in [R][Cc] -> out [Cc][R] ----
__global__ __launch_bounds__(256) void tconv_k(
    const float* __restrict__ in, unsigned short* __restrict__ out,
    int R, int Cc)
{
    __shared__ float t[64][65];
    const int r0 = blockIdx.y * 64, c0 = blockIdx.x * 64;
    const int tid = threadIdx.x;
    const int a = tid >> 4;
    const int b = tid & 15;
#pragma unroll
    for (int i = 0; i < 4; ++i) {
        const int row = a + i * 16;
        float4 v = *(const float4*)(in + (long long)(r0 + row) * Cc + c0 + b * 4);
        t[row][b * 4 + 0] = v.x; t[row][b * 4 + 1] = v.y;
        t[row][b * 4 + 2] = v.z; t[row][b * 4 + 3] = v.w;
    }
    __syncthreads();
#pragma unroll
    for (int i = 0; i < 4; ++i) {
        const int oc = a + i * 16;
        ushort4 o;
        o.x = f2bf(t[b * 4 + 0][oc]);
        o.y = f2bf(t[b * 4 + 1][oc]);
        o.z = f2bf(t[b * 4 + 2][oc]);
        o.w = f2bf(t[b * 4 + 3][oc]);
        *(ushort4*)(out + (long long)(c0 + oc) * R + r0 + b * 4) = o;
    }
}

// ------ bf16 transpose of the v-slice: qkv[8192][3072]@col2048 -> vT[1024][8192]
__global__ __launch_bounds__(256) void vtrans_k(
    const unsigned short* __restrict__ in, unsigned short* __restrict__ out)
{
    __shared__ unsigned short t[64][72];
    const int r0 = blockIdx.x * 64;       // rows of in (time)
    const int c0 = blockIdx.y * 64;       // cols of v (channel)
    const int tid = threadIdx.x;
#pragma unroll
    for (int i = 0; i < 2; ++i) {
        const int ch = tid * 2 + i;       // 0..511
        const int row = ch >> 3, cs = ch & 7;
        int4 v = *(const int4*)(in + (long long)(r0 + row) * 3072 + 2048 + c0 + cs * 8);
        *(int4*)&t[row][cs * 8] = v;      // 144B rows -> 16B-aligned slots
    }
    __syncthreads();
#pragma unroll
    for (int i = 0; i < 2; ++i) {
        const int w = tid * 2 + i;
        const int oc = w >> 3, orc = w & 7;
        unsigned short tmp[8];
#pragma unroll
        for (int j = 0; j < 8; ++j) tmp[j] = t[orc * 8 + j][oc];
        *(int4*)(out + (long long)(c0 + oc) * 8192 + r0 + orc * 8) = *(const int4*)tmp;
    }
}

// ---------------- LayerNorm: one wave per 1024-elem row ---------------------
__global__ __launch_bounds__(256) void ln_k(
    const float* __restrict__ x, const float* __restrict__ g,
    const float* __restrict__ be, unsigned short* __restrict__ out)
{
    const int wv = threadIdx.x >> 6, lane = threadIdx.x & 63;
    const long long row = blockIdx.x * 4 + wv;
    const float* xr = x + row * 1024;
    float4 v[4];
    float s = 0.f, q = 0.f;
#pragma unroll
    for (int j = 0; j < 4; ++j) {
        v[j] = *(const float4*)(xr + j * 256 + lane * 4);
        s += v[j].x + v[j].y + v[j].z + v[j].w;
        q += v[j].x * v[j].x + v[j].y * v[j].y + v[j].z * v[j].z + v[j].w * v[j].w;
    }
#pragma unroll
    for (int off = 32; off > 0; off >>= 1) {
        s += __shfl_xor(s, off);
        q += __shfl_xor(q, off);
    }
    const float mean = s * (1.0f / 1024.0f);
    const float var  = q * (1.0f / 1024.0f) - mean * mean;
    const float rstd = rsqrtf(var + 1e-5f);
#pragma unroll
    for (int j = 0; j < 4; ++j) {
        float4 gv = *(const float4*)(g + j * 256 + lane * 4);
        float4 bv = *(const float4*)(be + j * 256 + lane * 4);
        ushort4 o;
        o.x = f2bf((v[j].x - mean) * rstd * gv.x + bv.x);
        o.y = f2bf((v[j].y - mean) * rstd * gv.y + bv.y);
        o.z = f2bf((v[j].z - mean) * rstd * gv.z + bv.z);
        o.w = f2bf((v[j].w - mean) * rstd * gv.w + bv.w);
        *(ushort4*)(out + row * 1024 + j * 256 + lane * 4) = o;
    }
}

// ------------- causal row softmax: S bf16 -> P bf16 (zero-padded) ----------
__global__ __launch_bounds__(256) void softmax_k(
    const unsigned short* __restrict__ S, unsigned short* __restrict__ P, int T)
{
    __shared__ float rowl[2048];
    __shared__ float sred[4];
    const int t = blockIdx.x;
    const long long base = ((long long)blockIdx.y * T + t) * (long long)T;
    const unsigned short* srow = S + base;
    unsigned short* prow = P + base;
    const int n = t + 1;                       // valid causal length
    const int lim = ((t >> 8) + 1) << 8;       // zero-fill to 256 boundary
    const int tid = threadIdx.x;

    const int n8 = n >> 3;
    for (int i = tid; i < n8; i += 256) {
        int4 r = ((const int4*)srow)[i];
        const unsigned short* u = (const unsigned short*)&r;
#pragma unroll
        for (int j = 0; j < 8; ++j) rowl[i * 8 + j] = bf2f(u[j]);
    }
    for (int i = (n8 << 3) + tid; i < n; i += 256) rowl[i] = bf2f(srow[i]);
    __syncthreads();

    float mx = -3.0e38f;
    for (int i = tid; i < n; i += 256) mx = fmaxf(mx, rowl[i]);
#pragma unroll
    for (int off = 32; off > 0; off >>= 1) mx = fmaxf(mx, __shfl_xor(mx, off));
    if ((tid & 63) == 0) sred[tid >> 6] = mx;
    __syncthreads();
    mx = fmaxf(fmaxf(sred[0], sred[1]), fmaxf(sred[2], sred[3]));
    __syncthreads();

    float sum = 0.f;
    for (int i = tid; i < n; i += 256) {
        float e = __expf(rowl[i] - mx);
        rowl[i] = e;
        sum += e;
    }
#pragma unroll
    for (int off = 32; off > 0; off >>= 1) sum += __shfl_xor(sum, off);
    if ((tid & 63) == 0) sred[tid >> 6] = sum;
    __syncthreads();
    sum = sred[0] + sred[1] + sred[2] + sred[3];
    const float inv = 1.0f / sum;

    for (int i = tid; i < n; i += 256) prow[i] = f2bf(rowl[i] * inv);
    for (int i = n + tid; i < lim; i += 256) prow[i] = 0;
}

// -------- ff2 finalize: out = p0 + p1 + bias[col] + xres (all fp32) --------
__global__ __launch_bounds__(256) void ffadd_k(
    const float4* __restrict__ p0, const float4* __restrict__ p1,
    const float4* __restrict__ xr, const float4* __restrict__ b2,
    float4* __restrict__ out, int n4)
{
    int i = blockIdx.x * 256 + threadIdx.x;
    const int stride = gridDim.x * 256;
    for (; i < n4; i += stride) {
        float4 a = p0[i], b = p1[i], c = xr[i], d = b2[i & 255];
        float4 o;
        o.x = a.x + b.x + c.x + d.x;
        o.y = a.y + b.y + c.y + d.y;
        o.z = a.z + b.z + c.z + d.z;
        o.w = a.w + b.w + c.w + d.w;
        out[i] = o;
    }
}

// ---------------------------------------------------------------------------
extern "C" void kernel_launch(void* const* d_in, const int* in_sizes, int n_in,
                              void* d_out, int out_size, void* d_ws, size_t ws_size,
                              hipStream_t stream)
{
    const int B = 4, T = 2048, C = 1024, F = 4096;
    const float* x   = (const float*)d_in[0];
    const float* Wk  = (const float*)d_in[1];
    const float* Wq  = (const float*)d_in[2];
    const float* Wv  = (const float*)d_in[3];
    const float* W1  = (const float*)d_in[4];
    const float* b1  = (const float*)d_in[5];
    const float* W2  = (const float*)d_in[6];
    const float* b2  = (const float*)d_in[7];
    const float* g1  = (const float*)d_in[8];
    const float* be1 = (const float*)d_in[9];
    const float* g2  = (const float*)d_in[10];
    const float* be2 = (const float*)d_in[11];

    char* ws = (char*)d_ws;
    const size_t MB = 1ull << 20;
    unsigned short* h     = (unsigned short*)(ws + 0);         // 16 MiB
    unsigned short* qkv   = (unsigned short*)(ws + 16 * MB);   // 48 MiB [8192][3072]
    unsigned short* vT    = (unsigned short*)(ws + 64 * MB);   // 16 MiB [1024][8192]
    float*          pbuf  = (float*)(ws + 16 * MB);            // 64 MiB (aliases qkv+vT; used after pv)
    float*          xres  = (float*)(ws + 80 * MB);            // 32 MiB
    unsigned short* S     = (unsigned short*)(ws + 112 * MB);  // 32 MiB bf16 [B][T][T]
    unsigned short* P     = (unsigned short*)(ws + 144 * MB);  // 32 MiB
    unsigned short* ff1   = (unsigned short*)(ws + 112 * MB);  // 64 MiB (aliases S+P; used after pv)
    unsigned short* wqkvT = (unsigned short*)(ws + 176 * MB);  // 6 MiB [3C][C]
    unsigned short* w1T   = (unsigned short*)(ws + 182 * MB);  // 8 MiB [F][C]
    unsigned short* w2T   = (unsigned short*)(ws + 190 * MB);  // 8 MiB [C][F]  (end 198 MiB)

    // transposed weight converts (q,k,v fused into wqkvT)
    tconv_k<<<dim3(16, 16), 256, 0, stream>>>(Wq, wqkvT, C, C);
    tconv_k<<<dim3(16, 16), 256, 0, stream>>>(Wk, wqkvT + C * C, C, C);
    tconv_k<<<dim3(16, 16), 256, 0, stream>>>(Wv, wqkvT + 2 * C * C, C, C);
    tconv_k<<<dim3(64, 16), 256, 0, stream>>>(W1, w1T, C, F);
    tconv_k<<<dim3(16, 64), 256, 0, stream>>>(W2, w2T, F, C);

    // LN1
    ln_k<<<dim3(B * T / 4), 256, 0, stream>>>(x, g1, be1, h);

    // [q|k|v] = h @ [Wq|Wk|Wv]   (M=8192, N=3072, K=1024) -> 384 blocks
    dim3 gqkv(3 * C / 256, (B * T) / 256, 1);
    gemm256<EPI_BF16, false, false><<<gqkv, 512, 0, stream>>>(
        h, wqkvT, qkv, nullptr, nullptr, B * T, 3 * C, C, C, C, 1.0f, 0, 0, 0, 0);

    // vT = transpose of v-slice
    vtrans_k<<<dim3(B * T / 64, C / 64), 256, 0, stream>>>(qkv, vT);

    // S = q @ k^T / 32 (bf16 out; causal tiles only) -> 144 alive
    dim3 gsc(T / 256, T / 256, B);
    gemm256<EPI_BF16, true, false><<<gsc, 512, 0, stream>>>(
        qkv, qkv + C, S, nullptr, nullptr, T, T, C, 3 * C, 3 * C, 0.03125f,
        (long long)T * 3 * C, (long long)T * 3 * C, (long long)T * T, 0);

    // P = causal softmax(S)
    softmax_k<<<dim3(T, B), 256, 0, stream>>>(S, P, T);

    // xres = x + P @ v  (B = vT [C][8192], batch col-offset T) -> 128 blocks
    dim3 gsa(C / 256, T / 256, B);
    gemm256<EPI_RESID_F32, false, true><<<gsa, 512, 0, stream>>>(
        P, vT, xres, nullptr, x, T, C, T, T, B * T, 1.0f,
        (long long)T * T, (long long)T, (long long)T * C, (long long)T * C);

    // LN2
    ln_k<<<dim3(B * T / 4), 256, 0, stream>>>(xres, g2, be2, h);

    // ff1 = relu(h @ W1 + b1)   (M=8192, N=4096, K=1024) -> 512 blocks
    dim3 gf1(F / 256, (B * T) / 256, 1);
    gemm256<EPI_BIAS_RELU_BF16, false, false><<<gf1, 512, 0, stream>>>(
        h, w1T, ff1, b1, nullptr, B * T, F, C, C, C, 1.0f, 0, 0, 0, 0);

    // ff2 split-K z=2: partials = ff1[:, z*2048:] @ W2[z*2048:, :] -> 256 blocks
    dim3 gf2(C / 256, (B * T) / 256, 2);
    gemm256<EPI_F32, false, false><<<gf2, 512, 0, stream>>>(
        ff1, w2T, pbuf, nullptr, nullptr, B * T, C, F / 2, F, F, 1.0f,
        (long long)(F / 2), (long long)(F / 2), (long long)(B * T) * C, 0);

    // out = p0 + p1 + b2 + xres
    ffadd_k<<<dim3(2048), 256, 0, stream>>>(
        (const float4*)pbuf, (const float4*)(pbuf + (long long)(B * T) * C),
        (const float4*)xres, (const float4*)b2, (float4*)d_out,
        (B * T) * C / 4);
}